// Round 4
// baseline (633.135 us; speedup 1.0000x reference)
//
#include <hip/hip_runtime.h>
#include <math.h>

// Problem constants (fixed by reference): B=32, D=64, H=W=64, K=512
#define KC      512
#define DD      64
#define NROWS   131072      // B*H*W
#define HWN     4096        // H*W
#define BSTRIDE 262144      // D*H*W
#define TOTELEM 8388608.0f  // B*D*H*W

// ---- workspace layout (float offsets) ----
#define WS_ENORM  0         // [512]
#define WS_COUNTS 512       // [512]
#define WS_LOSS   1024      // [1]
#define WS_DW     1088      // [512*64]
#define WS_IDX    33856     // [131072] ints
#define WS_ZERO_BYTES 135424  // bytes covering [0, WS_DW+32768)

// ---- output layout (float offsets) ----
#define OUT_QUANT 0
#define OUT_LOSS  8388608
#define OUT_PERP  8388609
#define OUT_EMB   8388610
#define OUT_SM    8421378
#define OUT_EMAW  8421890

// K0: per-code squared norms
__global__ void k_enorm(const float* __restrict__ emb, float* __restrict__ enorm) {
    int k = blockIdx.x * blockDim.x + threadIdx.x;
    if (k >= KC) return;
    const float* r = emb + k * DD;
    float s0 = 0.f, s1 = 0.f, s2 = 0.f, s3 = 0.f;
#pragma unroll
    for (int d = 0; d < DD; d += 4) {
        s0 += r[d] * r[d];
        s1 += r[d + 1] * r[d + 1];
        s2 += r[d + 2] * r[d + 2];
        s3 += r[d + 3] * r[d + 3];
    }
    enorm[k] = (s0 + s1) + (s2 + s3);
}

// K1: argmin over codes for each row.
// Layout: 256 thr/block = 4 waves. Wave w handles row-group (blockIdx*2 + w>>1),
// code half (w&1)*256. Embedding operands are wave-uniform -> scalar loads
// (s_load_dwordx16), zero LDS traffic in the inner loop. Halves combine via LDS
// with strict < (ties -> lower code index, matching sequential first-min).
__global__ __launch_bounds__(256, 4) void k_argmin(
        const float* __restrict__ x, const float* __restrict__ emb,
        const float* __restrict__ enorm_g, float* __restrict__ counts,
        int* __restrict__ idx_out) {
    __shared__ float hist[KC];
    __shared__ float bbuf[4][64];
    __shared__ int   ibuf[4][64];

    const int tid  = threadIdx.x;
    const int w    = tid >> 6;
    const int lane = tid & 63;

    for (int i = tid; i < KC; i += 256) hist[i] = 0.f;

    const int rgroup = blockIdx.x * 2 + (w >> 1);
    const int n      = rgroup * 64 + lane;
    const int khalf  = (w & 1) * 256;

    const int b  = n >> 12;
    const int hw = n & 4095;
    const float* xp = x + b * BSTRIDE + hw;   // element (b, d, hw) at xp[d*4096]

    float row[DD];
    float f0 = 0.f, f1 = 0.f, f2 = 0.f, f3 = 0.f;
#pragma unroll
    for (int d = 0; d < DD; d += 4) {
        row[d]     = xp[d * HWN];
        row[d + 1] = xp[(d + 1) * HWN];
        row[d + 2] = xp[(d + 2) * HWN];
        row[d + 3] = xp[(d + 3) * HWN];
        f0 += row[d] * row[d];
        f1 += row[d + 1] * row[d + 1];
        f2 += row[d + 2] * row[d + 2];
        f3 += row[d + 3] * row[d + 3];
    }
    const float fn = (f0 + f1) + (f2 + f3);

    float best = 3.4e38f;
    int   bi   = khalf;
#pragma unroll 1
    for (int k = khalf; k < khalf + 256; ++k) {
        const float* e = emb + k * DD;   // wave-uniform address -> s_load
        float a0 = 0.f, a1 = 0.f, a2 = 0.f, a3 = 0.f;
#pragma unroll
        for (int d = 0; d < DD; d += 4) {
            a0 += row[d] * e[d];
            a1 += row[d + 1] * e[d + 1];
            a2 += row[d + 2] * e[d + 2];
            a3 += row[d + 3] * e[d + 3];
        }
        float dot  = (a0 + a1) + (a2 + a3);
        float dist = fn - 2.0f * dot + enorm_g[k];
        if (dist < best) { best = dist; bi = k; }   // strict <: first-min tie-break
    }

    bbuf[w][lane] = best;
    ibuf[w][lane] = bi;
    __syncthreads();

    if ((w & 1) == 0) {
        float b1 = bbuf[w | 1][lane];
        int   i1 = ibuf[w | 1][lane];
        if (b1 < best) { best = b1; bi = i1; }   // tie -> lower half's (lower) index
        idx_out[n] = bi;
        atomicAdd(&hist[bi], 1.0f);
    }
    __syncthreads();

    for (int i = tid; i < KC; i += 256) {
        float h = hist[i];
        if (h != 0.f) atomicAdd(&counts[i], h);  // integer-valued floats: exact
    }
}

// K2: quant_st write, loss partial, dw segment-sum.
// grid = B*D = 2048 blocks; block handles one (b,d) plane of 4096 elements.
__global__ void k_scatter(const float* __restrict__ x, const float* __restrict__ emb,
                          const int* __restrict__ idx, float* __restrict__ qout,
                          float* __restrict__ dw, float* __restrict__ loss_acc) {
    __shared__ float dwloc[KC];
    __shared__ float red[4];
    const int blk = blockIdx.x;
    const int b = blk >> 6, d = blk & 63;
    const int tid = threadIdx.x;   // 256

    for (int i = tid; i < KC; i += 256) dwloc[i] = 0.f;
    __syncthreads();

    const float* xp = x + b * BSTRIDE + d * HWN;
    float*       qp = qout + b * BSTRIDE + d * HWN;
    const int*   ip = idx + b * HWN;

    float ls = 0.f;
    for (int hw = tid; hw < HWN; hw += 256) {
        float xv = xp[hw];
        int   id = ip[hw];
        float ev = emb[id * DD + d];
        float t  = ev - xv;          // quant - x
        qp[hw]   = xv + t;           // x + (quant - x), matches reference rounding
        ls += t * t;
        atomicAdd(&dwloc[id], xv);
    }

    // block loss reduction: wave shuffle then 4-way LDS
#pragma unroll
    for (int o = 32; o > 0; o >>= 1) ls += __shfl_down(ls, o);
    if ((tid & 63) == 0) red[tid >> 6] = ls;
    __syncthreads();
    if (tid == 0) atomicAdd(loss_acc, (red[0] + red[1]) + (red[2] + red[3]));

    for (int i = tid; i < KC; i += 256) {
        float v = dwloc[i];
        if (v != 0.f) atomicAdd(&dw[i * DD + d], v);
    }
}

// K3: single block; scalars (loss, perplexity), smoothed cluster sizes.
__global__ void k_final(const float* __restrict__ counts, const float* __restrict__ ema_cs,
                        const float* __restrict__ loss_acc, float* __restrict__ out) {
    __shared__ float r1[8], r2[8];
    __shared__ float nb;
    const int t = threadIdx.x;   // 512

    float c   = counts[t];
    float ncs = 0.99f * ema_cs[t] + 0.01f * c;

    float s = ncs;
#pragma unroll
    for (int o = 32; o > 0; o >>= 1) s += __shfl_down(s, o);

    float p = c * (1.0f / 131072.0f);
    float e = (p > 0.f) ? p * logf(p) : 0.f;
#pragma unroll
    for (int o = 32; o > 0; o >>= 1) e += __shfl_down(e, o);

    if ((t & 63) == 0) { r1[t >> 6] = s; r2[t >> 6] = e; }
    __syncthreads();
    if (t == 0) {
        float n  = 0.f, es = 0.f;
#pragma unroll
        for (int i = 0; i < 8; ++i) { n += r1[i]; es += r2[i]; }
        nb = n;
        out[OUT_LOSS] = 0.25f * (loss_acc[0] / TOTELEM);
        out[OUT_PERP] = expf(-es);
    }
    __syncthreads();
    float n = nb;
    out[OUT_SM + t] = (ncs + 1e-5f) / (n + 0.00512f) * n;   // (ncs+EPS)/(n+K*EPS)*n
}

// K4: new_ema_w and new_embedding (32768 elements).
__global__ void k_emb(const float* __restrict__ ema_w, const float* __restrict__ dw,
                      const float* __restrict__ sm, float* __restrict__ out_emaw,
                      float* __restrict__ out_emb) {
    int i = blockIdx.x * 256 + threadIdx.x;
    float nw = 0.99f * ema_w[i] + 0.01f * dw[i];
    out_emaw[i] = nw;
    out_emb[i]  = nw / sm[i >> 6];
}

extern "C" void kernel_launch(void* const* d_in, const int* in_sizes, int n_in,
                              void* d_out, int out_size, void* d_ws, size_t ws_size,
                              hipStream_t stream) {
    const float* x      = (const float*)d_in[0];
    const float* emb    = (const float*)d_in[1];
    const float* ema_cs = (const float*)d_in[2];
    const float* ema_w  = (const float*)d_in[3];
    float* out = (float*)d_out;

    float* wsf     = (float*)d_ws;
    float* enorm   = wsf + WS_ENORM;
    float* counts  = wsf + WS_COUNTS;
    float* loss    = wsf + WS_LOSS;
    float* dw      = wsf + WS_DW;
    int*   idx     = (int*)(wsf + WS_IDX);

    hipMemsetAsync(d_ws, 0, WS_ZERO_BYTES, stream);

    k_enorm  <<<2,    256, 0, stream>>>(emb, enorm);
    k_argmin <<<1024, 256, 0, stream>>>(x, emb, enorm, counts, idx);
    k_scatter<<<2048, 256, 0, stream>>>(x, emb, idx, out + OUT_QUANT, dw, loss);
    k_final  <<<1,    512, 0, stream>>>(counts, ema_cs, loss, out);
    k_emb    <<<128,  256, 0, stream>>>(ema_w, dw, out + OUT_SM, out + OUT_EMAW,
                                        out + OUT_EMB);
}

// Round 5
// 173.166 us; speedup vs baseline: 3.6562x; 3.6562x over previous
//
#include <hip/hip_runtime.h>
#include <hip/hip_bf16.h>
#include <math.h>

typedef __attribute__((ext_vector_type(8))) short short8;
typedef __attribute__((ext_vector_type(4))) float f32x4;

// Problem constants: B=32, D=64, H=W=64, K=512
#define KC      512
#define DD      64
#define NROWS   131072
#define HWN     4096
#define BSTRIDE 262144
#define TOTELEM 8388608.0f
#define MARGIN  0.03f      // flag threshold; >> 6-sigma error of 3-pass bf16 split (~1e-3)

// ---- workspace layout (float offsets) ----
#define WS_COUNTS 0        // [512] f
#define WS_LOSS   512      // [1] f
#define WS_FLAGC  513      // [1] int
#define WS_DW     544      // [512*64] f
#define WS_ENORM  33312    // [512] f
#define WS_IDX    33824    // [131072] int
#define WS_EHL    164896   // [65536] short (bf16 hi/lo, B-frag order; byte off 659584, 16B aligned)
#define WS_LIST   197664   // [131072] int (refine list)
#define WS_ZERO_BYTES ((WS_DW + 32768) * 4)   // zero counts/loss/flagc/dw = 133248 B

// ---- output layout (float offsets) ----
#define OUT_QUANT 0
#define OUT_LOSS  8388608
#define OUT_PERP  8388609
#define OUT_EMB   8388610
#define OUT_SM    8421378
#define OUT_EMAW  8421890

// RNE float->bf16 split: v ~= hi + lo (each bf16), error ~2^-18 relative
__device__ __forceinline__ void bfsplit(float v, short& h, short& l) {
    unsigned u  = __float_as_uint(v);
    unsigned hb = (u + 0x7FFFu + ((u >> 16) & 1u)) & 0xFFFF0000u;
    h = (short)(hb >> 16);
    float lo = v - __uint_as_float(hb);
    unsigned u2 = __float_as_uint(lo);
    l = (short)((u2 + 0x7FFFu + ((u2 >> 16) & 1u)) >> 16);
}

// K0: per-code norms + embedding bf16 hi/lo in B-fragment order.
// ehl[((nt*2+ks)*2+h)*512 + lane*8 + i] = e_h[nt*16+(lane&15)][ks*32+(lane>>4)*8+i]
__global__ void k_prep(const float* __restrict__ emb, float* __restrict__ enorm,
                       short* __restrict__ ehl) {
    int k = blockIdx.x * 256 + threadIdx.x;
    if (k >= KC) return;
    const float* r = emb + k * DD;
    float s0 = 0.f, s1 = 0.f, s2 = 0.f, s3 = 0.f;
#pragma unroll
    for (int d = 0; d < DD; d += 4) {
        s0 += r[d] * r[d];
        s1 += r[d + 1] * r[d + 1];
        s2 += r[d + 2] * r[d + 2];
        s3 += r[d + 3] * r[d + 3];
    }
    enorm[k] = (s0 + s1) + (s2 + s3);
    int nt = k >> 4, cl = k & 15;
#pragma unroll
    for (int d = 0; d < DD; ++d) {
        short hh, ll;
        bfsplit(r[d], hh, ll);
        int ks = d >> 5, q = (d & 31) >> 3, i = d & 7;
        int lane = q * 16 + cl;
        ehl[((nt * 2 + ks) * 2 + 0) * 512 + lane * 8 + i] = hh;
        ehl[((nt * 2 + ks) * 2 + 1) * 512 + lane * 8 + i] = ll;
    }
}

// K1: MFMA argmin. 256 thr = 4 waves; wave handles 64 rows (4 m-tiles) x all 512 codes.
// 3-pass bf16 split into fp32 acc; best/second-best tracked; close calls flagged for refine.
__global__ __launch_bounds__(256, 2) void k_argmin_mfma(
        const float* __restrict__ x, const short* __restrict__ ehl,
        const float* __restrict__ enorm, int* __restrict__ idx_out,
        int* __restrict__ flagcnt, int* __restrict__ list) {
    const int tid  = threadIdx.x;
    const int w    = tid >> 6;
    const int lane = tid & 63;
    const int lm   = lane & 15, lq = lane >> 4;
    const int rowbase = blockIdx.x * 256 + w * 64;
    const int bb = rowbase >> 12, hw0 = rowbase & 4095;   // same b for whole wave
    const float* xb = x + bb * BSTRIDE + hw0;

    short8 ah[4][2], al[4][2];
    float  fnj[4][4];
#pragma unroll
    for (int mt = 0; mt < 4; ++mt) {
        float xv[16];
#pragma unroll
        for (int ks = 0; ks < 2; ++ks)
#pragma unroll
            for (int i = 0; i < 8; ++i) {
                int d = ks * 32 + lq * 8 + i;
                xv[ks * 8 + i] = xb[d * HWN + mt * 16 + lm];
            }
        float p0 = 0.f, p1 = 0.f, p2 = 0.f, p3 = 0.f;
#pragma unroll
        for (int t = 0; t < 16; t += 4) {
            p0 += xv[t] * xv[t];
            p1 += xv[t + 1] * xv[t + 1];
            p2 += xv[t + 2] * xv[t + 2];
            p3 += xv[t + 3] * xv[t + 3];
        }
        float fn = (p0 + p1) + (p2 + p3);
        fn += __shfl_xor(fn, 16);
        fn += __shfl_xor(fn, 32);           // lanes sharing lm now hold fn of row mt*16+lm
#pragma unroll
        for (int j = 0; j < 4; ++j) fnj[mt][j] = __shfl(fn, lq * 4 + j);
#pragma unroll
        for (int ks = 0; ks < 2; ++ks) {
            short8 h8, l8;
#pragma unroll
            for (int i = 0; i < 8; ++i) {
                short hh, ll;
                bfsplit(xv[ks * 8 + i], hh, ll);
                h8[i] = hh; l8[i] = ll;
            }
            ah[mt][ks] = h8; al[mt][ks] = l8;
        }
    }

    const short8* eb = (const short8*)ehl;
    float best[4][4], best2[4][4];
    int   bi[4][4];
#pragma unroll
    for (int mt = 0; mt < 4; ++mt)
#pragma unroll
        for (int j = 0; j < 4; ++j) { best[mt][j] = 3.4e38f; best2[mt][j] = 3.4e38f; bi[mt][j] = 0; }

#pragma unroll 2
    for (int nt = 0; nt < 32; ++nt) {
        short8 bh0 = eb[(nt * 4 + 0) * 64 + lane];
        short8 bl0 = eb[(nt * 4 + 1) * 64 + lane];
        short8 bh1 = eb[(nt * 4 + 2) * 64 + lane];
        short8 bl1 = eb[(nt * 4 + 3) * 64 + lane];
        float  en  = enorm[nt * 16 + lm];
        const int c = nt * 16 + lm;
#pragma unroll
        for (int mt = 0; mt < 4; ++mt) {
            f32x4 acc = {0.f, 0.f, 0.f, 0.f};
            acc = __builtin_amdgcn_mfma_f32_16x16x32_bf16(ah[mt][0], bh0, acc, 0, 0, 0);
            acc = __builtin_amdgcn_mfma_f32_16x16x32_bf16(al[mt][0], bh0, acc, 0, 0, 0);
            acc = __builtin_amdgcn_mfma_f32_16x16x32_bf16(ah[mt][0], bl0, acc, 0, 0, 0);
            acc = __builtin_amdgcn_mfma_f32_16x16x32_bf16(ah[mt][1], bh1, acc, 0, 0, 0);
            acc = __builtin_amdgcn_mfma_f32_16x16x32_bf16(al[mt][1], bh1, acc, 0, 0, 0);
            acc = __builtin_amdgcn_mfma_f32_16x16x32_bf16(ah[mt][1], bl1, acc, 0, 0, 0);
#pragma unroll
            for (int j = 0; j < 4; ++j) {
                float dist = fnj[mt][j] + en - 2.0f * acc[j];
                bool  lt   = dist < best[mt][j];
                best2[mt][j] = lt ? best[mt][j] : fminf(best2[mt][j], dist);
                bi[mt][j]    = lt ? c : bi[mt][j];
                best[mt][j]  = lt ? dist : best[mt][j];
            }
        }
    }

    // cross-lane (16-lane n-groups) argmin with first-min tie-break + true 2nd-best
#pragma unroll
    for (int mt = 0; mt < 4; ++mt)
#pragma unroll
        for (int j = 0; j < 4; ++j) {
            float b = best[mt][j], b2 = best2[mt][j];
            int   ii = bi[mt][j];
#pragma unroll
            for (int o = 1; o < 16; o <<= 1) {
                float ob  = __shfl_xor(b, o);
                float ob2 = __shfl_xor(b2, o);
                int   oi  = __shfl_xor(ii, o);
                bool take = (ob < b) || (ob == b && oi < ii);
                float lose = take ? b : ob;
                b2 = fminf(lose, fminf(b2, ob2));
                b  = take ? ob : b;
                ii = take ? oi : ii;
            }
            if (lm == 0) {
                int row = rowbase + mt * 16 + lq * 4 + j;
                idx_out[row] = ii;
                if (b2 - b < MARGIN) {
                    int p = atomicAdd(flagcnt, 1);
                    list[p] = row;
                }
            }
        }
}

// K2: exact fp32 re-argmin for flagged rows; one wave per row, lanes split codes.
__global__ void k_refine(const float* __restrict__ x, const float* __restrict__ emb,
                         const float* __restrict__ enorm, const int* __restrict__ list,
                         const int* __restrict__ flagcnt, int* __restrict__ idx_out) {
    const int gw   = (blockIdx.x * 256 + threadIdx.x) >> 6;
    const int lane = threadIdx.x & 63;
    const int nw   = gridDim.x * 4;
    const int total = *flagcnt;
    for (int t = gw; t < total; t += nw) {
        int row = list[t];
        int b = row >> 12, hw = row & 4095;
        const float* xp = x + b * BSTRIDE + hw;
        float r[64];
#pragma unroll
        for (int d = 0; d < 64; ++d) r[d] = xp[d * HWN];   // wave-uniform -> broadcast
        float f0 = 0.f, f1 = 0.f, f2 = 0.f, f3 = 0.f;
#pragma unroll
        for (int d = 0; d < 64; d += 4) {
            f0 += r[d] * r[d]; f1 += r[d + 1] * r[d + 1];
            f2 += r[d + 2] * r[d + 2]; f3 += r[d + 3] * r[d + 3];
        }
        float fn = (f0 + f1) + (f2 + f3);
        float best = 3.4e38f; int bi = 0;
        for (int c0 = 0; c0 < 8; ++c0) {
            int k = c0 * 64 + lane;
            const float* e = emb + k * DD;
            float a0 = 0.f, a1 = 0.f, a2 = 0.f, a3 = 0.f;
#pragma unroll
            for (int d = 0; d < 64; d += 4) {
                a0 += r[d] * e[d]; a1 += r[d + 1] * e[d + 1];
                a2 += r[d + 2] * e[d + 2]; a3 += r[d + 3] * e[d + 3];
            }
            float dist = fn - 2.0f * ((a0 + a1) + (a2 + a3)) + enorm[k];
            if (dist < best) { best = dist; bi = k; }
        }
#pragma unroll
        for (int o = 1; o < 64; o <<= 1) {
            float ob = __shfl_xor(best, o);
            int   oi = __shfl_xor(bi, o);
            if (ob < best || (ob == best && oi < bi)) { best = ob; bi = oi; }
        }
        if (lane == 0) idx_out[row] = bi;
    }
}

// K3: counts histogram from final idx
__global__ void k_hist(const int* __restrict__ idx, float* __restrict__ counts) {
    __shared__ float h[KC];
    const int tid = threadIdx.x;
    for (int i = tid; i < KC; i += 256) h[i] = 0.f;
    __syncthreads();
    const int stride = gridDim.x * 256;
    for (int t = blockIdx.x * 256 + tid; t < NROWS; t += stride)
        atomicAdd(&h[idx[t]], 1.0f);
    __syncthreads();
    for (int i = tid; i < KC; i += 256) {
        float v = h[i];
        if (v != 0.f) atomicAdd(&counts[i], v);   // integer-valued: exact
    }
}

// K4: quant_st write, loss partial, dw segment-sum. grid = B*D.
__global__ void k_scatter(const float* __restrict__ x, const float* __restrict__ emb,
                          const int* __restrict__ idx, float* __restrict__ qout,
                          float* __restrict__ dw, float* __restrict__ loss_acc) {
    __shared__ float dwloc[KC];
    __shared__ float red[4];
    const int blk = blockIdx.x;
    const int b = blk >> 6, d = blk & 63;
    const int tid = threadIdx.x;

    for (int i = tid; i < KC; i += 256) dwloc[i] = 0.f;
    __syncthreads();

    const float* xp = x + b * BSTRIDE + d * HWN;
    float*       qp = qout + b * BSTRIDE + d * HWN;
    const int*   ip = idx + b * HWN;

    float ls = 0.f;
    for (int hw = tid; hw < HWN; hw += 256) {
        float xv = xp[hw];
        int   id = ip[hw];
        float ev = emb[id * DD + d];
        float t  = ev - xv;
        qp[hw]   = xv + t;
        ls += t * t;
        atomicAdd(&dwloc[id], xv);
    }
#pragma unroll
    for (int o = 32; o > 0; o >>= 1) ls += __shfl_down(ls, o);
    if ((tid & 63) == 0) red[tid >> 6] = ls;
    __syncthreads();
    if (tid == 0) atomicAdd(loss_acc, (red[0] + red[1]) + (red[2] + red[3]));

    for (int i = tid; i < KC; i += 256) {
        float v = dwloc[i];
        if (v != 0.f) atomicAdd(&dw[i * DD + d], v);
    }
}

// K5: scalars + smoothed cluster sizes
__global__ void k_final(const float* __restrict__ counts, const float* __restrict__ ema_cs,
                        const float* __restrict__ loss_acc, float* __restrict__ out) {
    __shared__ float r1[8], r2[8];
    __shared__ float nb;
    const int t = threadIdx.x;   // 512

    float c   = counts[t];
    float ncs = 0.99f * ema_cs[t] + 0.01f * c;

    float s = ncs;
#pragma unroll
    for (int o = 32; o > 0; o >>= 1) s += __shfl_down(s, o);

    float p = c * (1.0f / 131072.0f);
    float e = (p > 0.f) ? p * logf(p) : 0.f;
#pragma unroll
    for (int o = 32; o > 0; o >>= 1) e += __shfl_down(e, o);

    if ((t & 63) == 0) { r1[t >> 6] = s; r2[t >> 6] = e; }
    __syncthreads();
    if (t == 0) {
        float n = 0.f, es = 0.f;
#pragma unroll
        for (int i = 0; i < 8; ++i) { n += r1[i]; es += r2[i]; }
        nb = n;
        out[OUT_LOSS] = 0.25f * (loss_acc[0] / TOTELEM);
        out[OUT_PERP] = expf(-es);
    }
    __syncthreads();
    float n = nb;
    out[OUT_SM + t] = (ncs + 1e-5f) / (n + 0.00512f) * n;
}

// K6: new_ema_w and new_embedding
__global__ void k_emb(const float* __restrict__ ema_w, const float* __restrict__ dw,
                      const float* __restrict__ sm, float* __restrict__ out_emaw,
                      float* __restrict__ out_emb) {
    int i = blockIdx.x * 256 + threadIdx.x;
    float nw = 0.99f * ema_w[i] + 0.01f * dw[i];
    out_emaw[i] = nw;
    out_emb[i]  = nw / sm[i >> 6];
}

extern "C" void kernel_launch(void* const* d_in, const int* in_sizes, int n_in,
                              void* d_out, int out_size, void* d_ws, size_t ws_size,
                              hipStream_t stream) {
    const float* x      = (const float*)d_in[0];
    const float* emb    = (const float*)d_in[1];
    const float* ema_cs = (const float*)d_in[2];
    const float* ema_w  = (const float*)d_in[3];
    float* out = (float*)d_out;

    float* wsf     = (float*)d_ws;
    float* counts  = wsf + WS_COUNTS;
    float* loss    = wsf + WS_LOSS;
    int*   flagcnt = (int*)(wsf + WS_FLAGC);
    float* dw      = wsf + WS_DW;
    float* enorm   = wsf + WS_ENORM;
    int*   idx     = (int*)(wsf + WS_IDX);
    short* ehl     = (short*)(wsf + WS_EHL);
    int*   list    = (int*)(wsf + WS_LIST);

    hipMemsetAsync(d_ws, 0, WS_ZERO_BYTES, stream);

    k_prep       <<<2,    256, 0, stream>>>(emb, enorm, ehl);
    k_argmin_mfma<<<512,  256, 0, stream>>>(x, ehl, enorm, idx, flagcnt, list);
    k_refine     <<<256,  256, 0, stream>>>(x, emb, enorm, list, flagcnt, idx);
    k_hist       <<<256,  256, 0, stream>>>(idx, counts);
    k_scatter    <<<2048, 256, 0, stream>>>(x, emb, idx, out + OUT_QUANT, dw, loss);
    k_final      <<<1,    512, 0, stream>>>(counts, ema_cs, loss, out);
    k_emb        <<<128,  256, 0, stream>>>(ema_w, dw, out + OUT_SM, out + OUT_EMAW,
                                            out + OUT_EMB);
}

// Round 6
// 165.086 us; speedup vs baseline: 3.8352x; 1.0489x over previous
//
#include <hip/hip_runtime.h>
#include <hip/hip_bf16.h>
#include <math.h>

typedef __attribute__((ext_vector_type(8))) short short8;
typedef __attribute__((ext_vector_type(4))) float f32x4;

// Problem constants: B=32, D=64, H=W=64, K=512
#define KC      512
#define DD      64
#define NROWS   131072
#define HWN     4096
#define BSTRIDE 262144
#define TOTELEM 8388608.0f
#define MARGIN  0.03f      // flag threshold; >> 6-sigma error of 3-pass bf16 split (~1e-3)

// ---- workspace layout (float offsets) ----
#define WS_LOSSBUF 0        // [256] f
#define WS_FLAGC   256      // [1] int
#define WS_CNTP    288      // [8*512] f   count partials
#define WS_DWP     4384     // [8*512*64] f dw partials
#define WS_ENORM   266528   // [512] f
#define WS_IDX     267040   // [131072] int
#define WS_EHL     398112   // [65536] short (bf16 hi/lo, B-frag order; byte off 1592448, 16B aligned)
#define WS_LIST    430880   // [131072] int (refine list)
#define WS_ZERO_BYTES (266528 * 4)   // zero lossbuf/flagc/cntp/dwp = 1066112 B

// ---- output layout (float offsets) ----
#define OUT_QUANT 0
#define OUT_LOSS  8388608
#define OUT_PERP  8388609
#define OUT_EMB   8388610
#define OUT_SM    8421378
#define OUT_EMAW  8421890

// RNE float->bf16 split: v ~= hi + lo (each bf16), error ~2^-18 relative
__device__ __forceinline__ void bfsplit(float v, short& h, short& l) {
    unsigned u  = __float_as_uint(v);
    unsigned hb = (u + 0x7FFFu + ((u >> 16) & 1u)) & 0xFFFF0000u;
    h = (short)(hb >> 16);
    float lo = v - __uint_as_float(hb);
    unsigned u2 = __float_as_uint(lo);
    l = (short)((u2 + 0x7FFFu + ((u2 >> 16) & 1u)) >> 16);
}

// K0: per-code norms + embedding bf16 hi/lo in B-fragment order.
__global__ void k_prep(const float* __restrict__ emb, float* __restrict__ enorm,
                       short* __restrict__ ehl) {
    int k = blockIdx.x * 256 + threadIdx.x;
    if (k >= KC) return;
    const float* r = emb + k * DD;
    float s0 = 0.f, s1 = 0.f, s2 = 0.f, s3 = 0.f;
#pragma unroll
    for (int d = 0; d < DD; d += 4) {
        s0 += r[d] * r[d];
        s1 += r[d + 1] * r[d + 1];
        s2 += r[d + 2] * r[d + 2];
        s3 += r[d + 3] * r[d + 3];
    }
    enorm[k] = (s0 + s1) + (s2 + s3);
    int nt = k >> 4, cl = k & 15;
#pragma unroll
    for (int d = 0; d < DD; ++d) {
        short hh, ll;
        bfsplit(r[d], hh, ll);
        int ks = d >> 5, q = (d & 31) >> 3, i = d & 7;
        int lane = q * 16 + cl;
        ehl[((nt * 2 + ks) * 2 + 0) * 512 + lane * 8 + i] = hh;
        ehl[((nt * 2 + ks) * 2 + 1) * 512 + lane * 8 + i] = ll;
    }
}

// K1: MFMA argmin (unchanged from R5 — passing, now for clean counters).
__global__ __launch_bounds__(256, 2) void k_argmin_mfma(
        const float* __restrict__ x, const short* __restrict__ ehl,
        const float* __restrict__ enorm, int* __restrict__ idx_out,
        int* __restrict__ flagcnt, int* __restrict__ list) {
    const int tid  = threadIdx.x;
    const int w    = tid >> 6;
    const int lane = tid & 63;
    const int lm   = lane & 15, lq = lane >> 4;
    const int rowbase = blockIdx.x * 256 + w * 64;
    const int bb = rowbase >> 12, hw0 = rowbase & 4095;
    const float* xb = x + bb * BSTRIDE + hw0;

    short8 ah[4][2], al[4][2];
    float  fnj[4][4];
#pragma unroll
    for (int mt = 0; mt < 4; ++mt) {
        float xv[16];
#pragma unroll
        for (int ks = 0; ks < 2; ++ks)
#pragma unroll
            for (int i = 0; i < 8; ++i) {
                int d = ks * 32 + lq * 8 + i;
                xv[ks * 8 + i] = xb[d * HWN + mt * 16 + lm];
            }
        float p0 = 0.f, p1 = 0.f, p2 = 0.f, p3 = 0.f;
#pragma unroll
        for (int t = 0; t < 16; t += 4) {
            p0 += xv[t] * xv[t];
            p1 += xv[t + 1] * xv[t + 1];
            p2 += xv[t + 2] * xv[t + 2];
            p3 += xv[t + 3] * xv[t + 3];
        }
        float fn = (p0 + p1) + (p2 + p3);
        fn += __shfl_xor(fn, 16);
        fn += __shfl_xor(fn, 32);
#pragma unroll
        for (int j = 0; j < 4; ++j) fnj[mt][j] = __shfl(fn, lq * 4 + j);
#pragma unroll
        for (int ks = 0; ks < 2; ++ks) {
            short8 h8, l8;
#pragma unroll
            for (int i = 0; i < 8; ++i) {
                short hh, ll;
                bfsplit(xv[ks * 8 + i], hh, ll);
                h8[i] = hh; l8[i] = ll;
            }
            ah[mt][ks] = h8; al[mt][ks] = l8;
        }
    }

    const short8* eb = (const short8*)ehl;
    float best[4][4], best2[4][4];
    int   bi[4][4];
#pragma unroll
    for (int mt = 0; mt < 4; ++mt)
#pragma unroll
        for (int j = 0; j < 4; ++j) { best[mt][j] = 3.4e38f; best2[mt][j] = 3.4e38f; bi[mt][j] = 0; }

#pragma unroll 2
    for (int nt = 0; nt < 32; ++nt) {
        short8 bh0 = eb[(nt * 4 + 0) * 64 + lane];
        short8 bl0 = eb[(nt * 4 + 1) * 64 + lane];
        short8 bh1 = eb[(nt * 4 + 2) * 64 + lane];
        short8 bl1 = eb[(nt * 4 + 3) * 64 + lane];
        float  en  = enorm[nt * 16 + lm];
        const int c = nt * 16 + lm;
#pragma unroll
        for (int mt = 0; mt < 4; ++mt) {
            f32x4 acc = {0.f, 0.f, 0.f, 0.f};
            acc = __builtin_amdgcn_mfma_f32_16x16x32_bf16(ah[mt][0], bh0, acc, 0, 0, 0);
            acc = __builtin_amdgcn_mfma_f32_16x16x32_bf16(al[mt][0], bh0, acc, 0, 0, 0);
            acc = __builtin_amdgcn_mfma_f32_16x16x32_bf16(ah[mt][0], bl0, acc, 0, 0, 0);
            acc = __builtin_amdgcn_mfma_f32_16x16x32_bf16(ah[mt][1], bh1, acc, 0, 0, 0);
            acc = __builtin_amdgcn_mfma_f32_16x16x32_bf16(al[mt][1], bh1, acc, 0, 0, 0);
            acc = __builtin_amdgcn_mfma_f32_16x16x32_bf16(ah[mt][1], bl1, acc, 0, 0, 0);
#pragma unroll
            for (int j = 0; j < 4; ++j) {
                float dist = fnj[mt][j] + en - 2.0f * acc[j];
                bool  lt   = dist < best[mt][j];
                best2[mt][j] = lt ? best[mt][j] : fminf(best2[mt][j], dist);
                bi[mt][j]    = lt ? c : bi[mt][j];
                best[mt][j]  = lt ? dist : best[mt][j];
            }
        }
    }

#pragma unroll
    for (int mt = 0; mt < 4; ++mt)
#pragma unroll
        for (int j = 0; j < 4; ++j) {
            float b = best[mt][j], b2 = best2[mt][j];
            int   ii = bi[mt][j];
#pragma unroll
            for (int o = 1; o < 16; o <<= 1) {
                float ob  = __shfl_xor(b, o);
                float ob2 = __shfl_xor(b2, o);
                int   oi  = __shfl_xor(ii, o);
                bool take = (ob < b) || (ob == b && oi < ii);
                float lose = take ? b : ob;
                b2 = fminf(lose, fminf(b2, ob2));
                b  = take ? ob : b;
                ii = take ? oi : ii;
            }
            if (lm == 0) {
                int row = rowbase + mt * 16 + lq * 4 + j;
                idx_out[row] = ii;
                if (b2 - b < MARGIN) {
                    int p = atomicAdd(flagcnt, 1);
                    list[p] = row;
                }
            }
        }
}

// K2: exact fp32 re-argmin for flagged rows.
__global__ void k_refine(const float* __restrict__ x, const float* __restrict__ emb,
                         const float* __restrict__ enorm, const int* __restrict__ list,
                         const int* __restrict__ flagcnt, int* __restrict__ idx_out) {
    const int gw   = (blockIdx.x * 256 + threadIdx.x) >> 6;
    const int lane = threadIdx.x & 63;
    const int nw   = gridDim.x * 4;
    const int total = *flagcnt;
    for (int t = gw; t < total; t += nw) {
        int row = list[t];
        int b = row >> 12, hw = row & 4095;
        const float* xp = x + b * BSTRIDE + hw;
        float r[64];
#pragma unroll
        for (int d = 0; d < 64; ++d) r[d] = xp[d * HWN];
        float f0 = 0.f, f1 = 0.f, f2 = 0.f, f3 = 0.f;
#pragma unroll
        for (int d = 0; d < 64; d += 4) {
            f0 += r[d] * r[d]; f1 += r[d + 1] * r[d + 1];
            f2 += r[d + 2] * r[d + 2]; f3 += r[d + 3] * r[d + 3];
        }
        float fn = (f0 + f1) + (f2 + f3);
        float best = 3.4e38f; int bi = 0;
        for (int c0 = 0; c0 < 8; ++c0) {
            int k = c0 * 64 + lane;
            const float* e = emb + k * DD;
            float a0 = 0.f, a1 = 0.f, a2 = 0.f, a3 = 0.f;
#pragma unroll
            for (int d = 0; d < 64; d += 4) {
                a0 += r[d] * e[d]; a1 += r[d + 1] * e[d + 1];
                a2 += r[d + 2] * e[d + 2]; a3 += r[d + 3] * e[d + 3];
            }
            float dist = fn - 2.0f * ((a0 + a1) + (a2 + a3)) + enorm[k];
            if (dist < best) { best = dist; bi = k; }
        }
#pragma unroll
        for (int o = 1; o < 64; o <<= 1) {
            float ob = __shfl_xor(best, o);
            int   oi = __shfl_xor(bi, o);
            if (ob < best || (ob == best && oi < bi)) { best = ob; bi = oi; }
        }
        if (lane == 0) idx_out[row] = bi;
    }
}

// K3: counts histogram -> 8-way partials (64 blocks, low flush contention)
__global__ void k_hist(const int* __restrict__ idx, float* __restrict__ cntp) {
    __shared__ float h[KC];
    const int tid = threadIdx.x;
    for (int i = tid; i < KC; i += 256) h[i] = 0.f;
    __syncthreads();
    const int stride = gridDim.x * 256;
    for (int t = blockIdx.x * 256 + tid; t < NROWS; t += stride)
        atomicAdd(&h[idx[t]], 1.0f);
    __syncthreads();
    float* cp = cntp + (blockIdx.x & 7) * KC;
    for (int i = tid; i < KC; i += 256) {
        float v = h[i];
        if (v != 0.f) atomicAdd(&cp[i], v);   // integer-valued: exact
    }
}

// K4: quant_st + loss + dw. LDS-staged emb column; dw flushed to 8-way partials.
__global__ void k_scatter(const float* __restrict__ x, const float* __restrict__ emb,
                          const int* __restrict__ idx, float* __restrict__ qout,
                          float* __restrict__ dwp, float* __restrict__ lossbuf) {
    __shared__ float dwloc[KC];
    __shared__ float ecol[KC];
    __shared__ float red[4];
    const int blk = blockIdx.x;
    const int b = blk >> 6, d = blk & 63;
    const int tid = threadIdx.x;   // 256

    for (int i = tid; i < KC; i += 256) {
        dwloc[i] = 0.f;
        ecol[i]  = emb[i * DD + d];   // stride-256B, L2-resident table
    }
    __syncthreads();

    const float* xp = x + b * BSTRIDE + d * HWN;
    float*       qp = qout + b * BSTRIDE + d * HWN;
    const int*   ip = idx + b * HWN;

    float ls = 0.f;
    for (int hw = tid; hw < HWN; hw += 256) {
        float xv = xp[hw];
        int   id = ip[hw];
        float ev = ecol[id];         // LDS gather (cheap) instead of global
        float t  = ev - xv;
        qp[hw]   = xv + t;           // x + (quant - x), matches reference rounding
        ls += t * t;
        atomicAdd(&dwloc[id], xv);
    }

#pragma unroll
    for (int o = 32; o > 0; o >>= 1) ls += __shfl_down(ls, o);
    if ((tid & 63) == 0) red[tid >> 6] = ls;
    __syncthreads();
    if (tid == 0)
        atomicAdd(&lossbuf[blk & 255], (red[0] + red[1]) + (red[2] + red[3]));

    float* dp = dwp + (b & 7) * (KC * DD);
    for (int i = tid; i < KC; i += 256) {
        float v = dwloc[i];
        if (v != 0.f) atomicAdd(&dp[i * DD + d], v);   // 8-way spread partials
    }
}

// K5: scalars + smoothed cluster sizes (reads count partials + loss partials)
__global__ void k_final(const float* __restrict__ cntp, const float* __restrict__ ema_cs,
                        const float* __restrict__ lossbuf, float* __restrict__ out) {
    __shared__ float r1[8], r2[8], r3[8];
    __shared__ float nb;
    const int t = threadIdx.x;   // 512

    float c = 0.f;
#pragma unroll
    for (int g = 0; g < 8; ++g) c += cntp[g * KC + t];
    float ncs = 0.99f * ema_cs[t] + 0.01f * c;

    float s = ncs;
    float p = c * (1.0f / 131072.0f);
    float e = (p > 0.f) ? p * logf(p) : 0.f;
    float lv = (t < 256) ? lossbuf[t] : 0.f;
#pragma unroll
    for (int o = 32; o > 0; o >>= 1) {
        s  += __shfl_down(s, o);
        e  += __shfl_down(e, o);
        lv += __shfl_down(lv, o);
    }
    if ((t & 63) == 0) { int w = t >> 6; r1[w] = s; r2[w] = e; r3[w] = lv; }
    __syncthreads();
    if (t == 0) {
        float n = 0.f, es = 0.f, lt = 0.f;
#pragma unroll
        for (int i = 0; i < 8; ++i) { n += r1[i]; es += r2[i]; lt += r3[i]; }
        nb = n;
        out[OUT_LOSS] = 0.25f * (lt / TOTELEM);
        out[OUT_PERP] = expf(-es);
    }
    __syncthreads();
    float n = nb;
    out[OUT_SM + t] = (ncs + 1e-5f) / (n + 0.00512f) * n;
}

// K6: reduce dw partials + new_ema_w + new_embedding (coalesced throughout)
__global__ void k_emb(const float* __restrict__ ema_w, const float* __restrict__ dwp,
                      const float* __restrict__ sm, float* __restrict__ out_emaw,
                      float* __restrict__ out_emb) {
    int i = blockIdx.x * 256 + threadIdx.x;
    float dw = 0.f;
#pragma unroll
    for (int g = 0; g < 8; ++g) dw += dwp[g * (KC * DD) + i];
    float nw = 0.99f * ema_w[i] + 0.01f * dw;
    out_emaw[i] = nw;
    out_emb[i]  = nw / sm[i >> 6];
}

extern "C" void kernel_launch(void* const* d_in, const int* in_sizes, int n_in,
                              void* d_out, int out_size, void* d_ws, size_t ws_size,
                              hipStream_t stream) {
    const float* x      = (const float*)d_in[0];
    const float* emb    = (const float*)d_in[1];
    const float* ema_cs = (const float*)d_in[2];
    const float* ema_w  = (const float*)d_in[3];
    float* out = (float*)d_out;

    float* wsf     = (float*)d_ws;
    float* lossbuf = wsf + WS_LOSSBUF;
    int*   flagcnt = (int*)(wsf + WS_FLAGC);
    float* cntp    = wsf + WS_CNTP;
    float* dwp     = wsf + WS_DWP;
    float* enorm   = wsf + WS_ENORM;
    int*   idx     = (int*)(wsf + WS_IDX);
    short* ehl     = (short*)(wsf + WS_EHL);
    int*   list    = (int*)(wsf + WS_LIST);

    hipMemsetAsync(d_ws, 0, WS_ZERO_BYTES, stream);

    k_prep       <<<2,    256, 0, stream>>>(emb, enorm, ehl);
    k_argmin_mfma<<<512,  256, 0, stream>>>(x, ehl, enorm, idx, flagcnt, list);
    k_refine     <<<256,  256, 0, stream>>>(x, emb, enorm, list, flagcnt, idx);
    k_hist       <<<64,   256, 0, stream>>>(idx, cntp);
    k_scatter    <<<2048, 256, 0, stream>>>(x, emb, idx, out + OUT_QUANT, dwp, lossbuf);
    k_final      <<<1,    512, 0, stream>>>(cntp, ema_cs, lossbuf, out);
    k_emb        <<<128,  256, 0, stream>>>(ema_w, dwp, out + OUT_SM, out + OUT_EMAW,
                                            out + OUT_EMB);
}

// Round 7
// 136.869 us; speedup vs baseline: 4.6258x; 1.2062x over previous
//
#include <hip/hip_runtime.h>
#include <hip/hip_bf16.h>
#include <math.h>

typedef __attribute__((ext_vector_type(8))) short short8;
typedef __attribute__((ext_vector_type(4))) float f32x4;

// Problem constants: B=32, D=64, H=W=64, K=512
#define KC      512
#define DD      64
#define NROWS   131072
#define HWN     4096
#define BSTRIDE 262144
#define TOTELEM 8388608.0f
#define MARGIN  0.03f      // flag threshold; >> 6-sigma error of 3-pass bf16 split (~1e-3)

// ---- workspace layout (float offsets) ----
#define WS_LOSSBUF 0        // [512] f   per-block loss partials (plain stores)
#define WS_FLAGC   512      // [1] int   (pad to 544)
#define WS_CNTP    544      // [8*512] f count partials (atomics, zeroed)
#define WS_DWP     4640     // [8*64*512] f dw partials dwp[g][d][k] (plain stores)
#define WS_ENORM   266784   // [512] f
#define WS_IDX     267296   // [131072] int
#define WS_EHL     398368   // [65536] short, byte off 1593472 (16B aligned)
#define WS_LIST    431136   // [131072] int (refine list)
#define WS_ZERO_BYTES 18560 // zero lossbuf/flagc/cntp only

// ---- output layout (float offsets) ----
#define OUT_QUANT 0
#define OUT_LOSS  8388608
#define OUT_PERP  8388609
#define OUT_EMB   8388610
#define OUT_SM    8421378
#define OUT_EMAW  8421890

// RNE float->bf16 split: v ~= hi + lo (each bf16), error ~2^-18 relative
__device__ __forceinline__ void bfsplit(float v, short& h, short& l) {
    unsigned u  = __float_as_uint(v);
    unsigned hb = (u + 0x7FFFu + ((u >> 16) & 1u)) & 0xFFFF0000u;
    h = (short)(hb >> 16);
    float lo = v - __uint_as_float(hb);
    unsigned u2 = __float_as_uint(lo);
    l = (short)((u2 + 0x7FFFu + ((u2 >> 16) & 1u)) >> 16);
}

// K0: per-code norms + embedding bf16 hi/lo in B-fragment order.
__global__ void k_prep(const float* __restrict__ emb, float* __restrict__ enorm,
                       short* __restrict__ ehl) {
    int k = blockIdx.x * 256 + threadIdx.x;
    if (k >= KC) return;
    const float* r = emb + k * DD;
    float s0 = 0.f, s1 = 0.f, s2 = 0.f, s3 = 0.f;
#pragma unroll
    for (int d = 0; d < DD; d += 4) {
        s0 += r[d] * r[d];
        s1 += r[d + 1] * r[d + 1];
        s2 += r[d + 2] * r[d + 2];
        s3 += r[d + 3] * r[d + 3];
    }
    enorm[k] = (s0 + s1) + (s2 + s3);
    int nt = k >> 4, cl = k & 15;
#pragma unroll
    for (int d = 0; d < DD; ++d) {
        short hh, ll;
        bfsplit(r[d], hh, ll);
        int ks = d >> 5, q = (d & 31) >> 3, i = d & 7;
        int lane = q * 16 + cl;
        ehl[((nt * 2 + ks) * 2 + 0) * 512 + lane * 8 + i] = hh;
        ehl[((nt * 2 + ks) * 2 + 1) * 512 + lane * 8 + i] = ll;
    }
}

// K1: MFMA argmin (unchanged — passing since R5).
__global__ __launch_bounds__(256, 2) void k_argmin_mfma(
        const float* __restrict__ x, const short* __restrict__ ehl,
        const float* __restrict__ enorm, int* __restrict__ idx_out,
        int* __restrict__ flagcnt, int* __restrict__ list) {
    const int tid  = threadIdx.x;
    const int w    = tid >> 6;
    const int lane = tid & 63;
    const int lm   = lane & 15, lq = lane >> 4;
    const int rowbase = blockIdx.x * 256 + w * 64;
    const int bb = rowbase >> 12, hw0 = rowbase & 4095;
    const float* xb = x + bb * BSTRIDE + hw0;

    short8 ah[4][2], al[4][2];
    float  fnj[4][4];
#pragma unroll
    for (int mt = 0; mt < 4; ++mt) {
        float xv[16];
#pragma unroll
        for (int ks = 0; ks < 2; ++ks)
#pragma unroll
            for (int i = 0; i < 8; ++i) {
                int d = ks * 32 + lq * 8 + i;
                xv[ks * 8 + i] = xb[d * HWN + mt * 16 + lm];
            }
        float p0 = 0.f, p1 = 0.f, p2 = 0.f, p3 = 0.f;
#pragma unroll
        for (int t = 0; t < 16; t += 4) {
            p0 += xv[t] * xv[t];
            p1 += xv[t + 1] * xv[t + 1];
            p2 += xv[t + 2] * xv[t + 2];
            p3 += xv[t + 3] * xv[t + 3];
        }
        float fn = (p0 + p1) + (p2 + p3);
        fn += __shfl_xor(fn, 16);
        fn += __shfl_xor(fn, 32);
#pragma unroll
        for (int j = 0; j < 4; ++j) fnj[mt][j] = __shfl(fn, lq * 4 + j);
#pragma unroll
        for (int ks = 0; ks < 2; ++ks) {
            short8 h8, l8;
#pragma unroll
            for (int i = 0; i < 8; ++i) {
                short hh, ll;
                bfsplit(xv[ks * 8 + i], hh, ll);
                h8[i] = hh; l8[i] = ll;
            }
            ah[mt][ks] = h8; al[mt][ks] = l8;
        }
    }

    const short8* eb = (const short8*)ehl;
    float best[4][4], best2[4][4];
    int   bi[4][4];
#pragma unroll
    for (int mt = 0; mt < 4; ++mt)
#pragma unroll
        for (int j = 0; j < 4; ++j) { best[mt][j] = 3.4e38f; best2[mt][j] = 3.4e38f; bi[mt][j] = 0; }

#pragma unroll 2
    for (int nt = 0; nt < 32; ++nt) {
        short8 bh0 = eb[(nt * 4 + 0) * 64 + lane];
        short8 bl0 = eb[(nt * 4 + 1) * 64 + lane];
        short8 bh1 = eb[(nt * 4 + 2) * 64 + lane];
        short8 bl1 = eb[(nt * 4 + 3) * 64 + lane];
        float  en  = enorm[nt * 16 + lm];
        const int c = nt * 16 + lm;
#pragma unroll
        for (int mt = 0; mt < 4; ++mt) {
            f32x4 acc = {0.f, 0.f, 0.f, 0.f};
            acc = __builtin_amdgcn_mfma_f32_16x16x32_bf16(ah[mt][0], bh0, acc, 0, 0, 0);
            acc = __builtin_amdgcn_mfma_f32_16x16x32_bf16(al[mt][0], bh0, acc, 0, 0, 0);
            acc = __builtin_amdgcn_mfma_f32_16x16x32_bf16(ah[mt][0], bl0, acc, 0, 0, 0);
            acc = __builtin_amdgcn_mfma_f32_16x16x32_bf16(ah[mt][1], bh1, acc, 0, 0, 0);
            acc = __builtin_amdgcn_mfma_f32_16x16x32_bf16(al[mt][1], bh1, acc, 0, 0, 0);
            acc = __builtin_amdgcn_mfma_f32_16x16x32_bf16(ah[mt][1], bl1, acc, 0, 0, 0);
#pragma unroll
            for (int j = 0; j < 4; ++j) {
                float dist = fnj[mt][j] + en - 2.0f * acc[j];
                bool  lt   = dist < best[mt][j];
                best2[mt][j] = lt ? best[mt][j] : fminf(best2[mt][j], dist);
                bi[mt][j]    = lt ? c : bi[mt][j];
                best[mt][j]  = lt ? dist : best[mt][j];
            }
        }
    }

#pragma unroll
    for (int mt = 0; mt < 4; ++mt)
#pragma unroll
        for (int j = 0; j < 4; ++j) {
            float b = best[mt][j], b2 = best2[mt][j];
            int   ii = bi[mt][j];
#pragma unroll
            for (int o = 1; o < 16; o <<= 1) {
                float ob  = __shfl_xor(b, o);
                float ob2 = __shfl_xor(b2, o);
                int   oi  = __shfl_xor(ii, o);
                bool take = (ob < b) || (ob == b && oi < ii);
                float lose = take ? b : ob;
                b2 = fminf(lose, fminf(b2, ob2));
                b  = take ? ob : b;
                ii = take ? oi : ii;
            }
            if (lm == 0) {
                int row = rowbase + mt * 16 + lq * 4 + j;
                idx_out[row] = ii;
                if (b2 - b < MARGIN) {
                    int p = atomicAdd(flagcnt, 1);
                    list[p] = row;
                }
            }
        }
}

// K2: exact fp32 re-argmin for flagged rows.
__global__ void k_refine(const float* __restrict__ x, const float* __restrict__ emb,
                         const float* __restrict__ enorm, const int* __restrict__ list,
                         const int* __restrict__ flagcnt, int* __restrict__ idx_out) {
    const int gw   = (blockIdx.x * 256 + threadIdx.x) >> 6;
    const int lane = threadIdx.x & 63;
    const int nw   = gridDim.x * 4;
    const int total = *flagcnt;
    for (int t = gw; t < total; t += nw) {
        int row = list[t];
        int b = row >> 12, hw = row & 4095;
        const float* xp = x + b * BSTRIDE + hw;
        float r[64];
#pragma unroll
        for (int d = 0; d < 64; ++d) r[d] = xp[d * HWN];
        float f0 = 0.f, f1 = 0.f, f2 = 0.f, f3 = 0.f;
#pragma unroll
        for (int d = 0; d < 64; d += 4) {
            f0 += r[d] * r[d]; f1 += r[d + 1] * r[d + 1];
            f2 += r[d + 2] * r[d + 2]; f3 += r[d + 3] * r[d + 3];
        }
        float fn = (f0 + f1) + (f2 + f3);
        float best = 3.4e38f; int bi = 0;
        for (int c0 = 0; c0 < 8; ++c0) {
            int k = c0 * 64 + lane;
            const float* e = emb + k * DD;
            float a0 = 0.f, a1 = 0.f, a2 = 0.f, a3 = 0.f;
#pragma unroll
            for (int d = 0; d < 64; d += 4) {
                a0 += r[d] * e[d]; a1 += r[d + 1] * e[d + 1];
                a2 += r[d + 2] * e[d + 2]; a3 += r[d + 3] * e[d + 3];
            }
            float dist = fn - 2.0f * ((a0 + a1) + (a2 + a3)) + enorm[k];
            if (dist < best) { best = dist; bi = k; }
        }
#pragma unroll
        for (int o = 1; o < 64; o <<= 1) {
            float ob = __shfl_xor(best, o);
            int   oi = __shfl_xor(bi, o);
            if (ob < best || (ob == best && oi < bi)) { best = ob; bi = oi; }
        }
        if (lane == 0) idx_out[row] = bi;
    }
}

// K3: counts histogram -> 8-way partials
__global__ void k_hist(const int* __restrict__ idx, float* __restrict__ cntp) {
    __shared__ float h[KC];
    const int tid = threadIdx.x;
    for (int i = tid; i < KC; i += 256) h[i] = 0.f;
    __syncthreads();
    const int stride = gridDim.x * 256;
    for (int t = blockIdx.x * 256 + tid; t < NROWS; t += stride)
        atomicAdd(&h[idx[t]], 1.0f);
    __syncthreads();
    float* cp = cntp + (blockIdx.x & 7) * KC;
    for (int i = tid; i < KC; i += 256) {
        float v = h[i];
        if (v != 0.f) atomicAdd(&cp[i], v);   // integer-valued: exact
    }
}

// K4: quant_st + loss + dw. ZERO global atomics.
// 512 blocks x 512 thr: block (g,d) handles d-plane of 4 b's (b = 4g..4g+3).
// float4/int4 streaming; dwloc accumulated in LDS across the 4 planes, then
// ONE plain coalesced 2KB store to dwp[g][d][*]. Loss -> plain per-block slot.
__global__ __launch_bounds__(512) void k_scatter(
        const float* __restrict__ x, const float* __restrict__ emb,
        const int* __restrict__ idx, float* __restrict__ qout,
        float* __restrict__ dwp, float* __restrict__ lossbuf) {
    __shared__ float dwloc[KC];
    __shared__ float ecol[KC];
    __shared__ float red[8];
    const int bid = blockIdx.x;
    const int d = bid & 63, g = bid >> 6;     // g in 0..7
    const int tid = threadIdx.x;              // 512

    dwloc[tid] = 0.f;
    ecol[tid]  = emb[tid * DD + d];           // L2-resident column gather, once
    __syncthreads();

    float ls = 0.f;
#pragma unroll
    for (int bp = 0; bp < 4; ++bp) {
        const int b = g * 4 + bp;
        const float4* xp4 = (const float4*)(x + b * BSTRIDE + d * HWN);
        float4*       qp4 = (float4*)(qout + b * BSTRIDE + d * HWN);
        const int4*   ip4 = (const int4*)(idx + b * HWN);
#pragma unroll
        for (int it = 0; it < 2; ++it) {
            int c4 = it * 512 + tid;          // 1024 float4 per plane
            float4 xv = xp4[c4];
            int4   iv = ip4[c4];
            float4 qv;
            float e0 = ecol[iv.x], e1 = ecol[iv.y], e2 = ecol[iv.z], e3 = ecol[iv.w];
            float t0 = e0 - xv.x, t1 = e1 - xv.y, t2 = e2 - xv.z, t3 = e3 - xv.w;
            qv.x = xv.x + t0; qv.y = xv.y + t1; qv.z = xv.z + t2; qv.w = xv.w + t3;
            qp4[c4] = qv;
            ls += t0 * t0 + t1 * t1 + t2 * t2 + t3 * t3;
            atomicAdd(&dwloc[iv.x], xv.x);
            atomicAdd(&dwloc[iv.y], xv.y);
            atomicAdd(&dwloc[iv.z], xv.z);
            atomicAdd(&dwloc[iv.w], xv.w);
        }
    }

#pragma unroll
    for (int o = 32; o > 0; o >>= 1) ls += __shfl_down(ls, o);
    if ((tid & 63) == 0) red[tid >> 6] = ls;
    __syncthreads();
    if (tid == 0) {
        float s = 0.f;
#pragma unroll
        for (int i = 0; i < 8; ++i) s += red[i];
        lossbuf[bid] = s;                      // plain store, no atomic
    }
    dwp[(g * DD + d) * KC + tid] = dwloc[tid]; // plain coalesced 2KB store
}

// K5: scalars + smoothed cluster sizes
__global__ void k_final(const float* __restrict__ cntp, const float* __restrict__ ema_cs,
                        const float* __restrict__ lossbuf, float* __restrict__ out) {
    __shared__ float r1[8], r2[8], r3[8];
    __shared__ float nb;
    const int t = threadIdx.x;   // 512

    float c = 0.f;
#pragma unroll
    for (int g = 0; g < 8; ++g) c += cntp[g * KC + t];
    float ncs = 0.99f * ema_cs[t] + 0.01f * c;

    float s = ncs;
    float p = c * (1.0f / 131072.0f);
    float e = (p > 0.f) ? p * logf(p) : 0.f;
    float lv = lossbuf[t];
#pragma unroll
    for (int o = 32; o > 0; o >>= 1) {
        s  += __shfl_down(s, o);
        e  += __shfl_down(e, o);
        lv += __shfl_down(lv, o);
    }
    if ((t & 63) == 0) { int w = t >> 6; r1[w] = s; r2[w] = e; r3[w] = lv; }
    __syncthreads();
    if (t == 0) {
        float n = 0.f, es = 0.f, lt = 0.f;
#pragma unroll
        for (int i = 0; i < 8; ++i) { n += r1[i]; es += r2[i]; lt += r3[i]; }
        nb = n;
        out[OUT_LOSS] = 0.25f * (lt / TOTELEM);
        out[OUT_PERP] = expf(-es);
    }
    __syncthreads();
    float n = nb;
    out[OUT_SM + t] = (ncs + 1e-5f) / (n + 0.00512f) * n;
}

// K6: reduce dw partials + new_ema_w + new_embedding
__global__ void k_emb(const float* __restrict__ ema_w, const float* __restrict__ dwp,
                      const float* __restrict__ sm, float* __restrict__ out_emaw,
                      float* __restrict__ out_emb) {
    int i = blockIdx.x * 256 + threadIdx.x;   // i = k*64 + d
    int k = i >> 6, d = i & 63;
    float dw = 0.f;
#pragma unroll
    for (int g = 0; g < 8; ++g) dw += dwp[(g * DD + d) * KC + k];
    float nw = 0.99f * ema_w[i] + 0.01f * dw;
    out_emaw[i] = nw;
    out_emb[i]  = nw / sm[k];
}

extern "C" void kernel_launch(void* const* d_in, const int* in_sizes, int n_in,
                              void* d_out, int out_size, void* d_ws, size_t ws_size,
                              hipStream_t stream) {
    const float* x      = (const float*)d_in[0];
    const float* emb    = (const float*)d_in[1];
    const float* ema_cs = (const float*)d_in[2];
    const float* ema_w  = (const float*)d_in[3];
    float* out = (float*)d_out;

    float* wsf     = (float*)d_ws;
    float* lossbuf = wsf + WS_LOSSBUF;
    int*   flagcnt = (int*)(wsf + WS_FLAGC);
    float* cntp    = wsf + WS_CNTP;
    float* dwp     = wsf + WS_DWP;
    float* enorm   = wsf + WS_ENORM;
    int*   idx     = (int*)(wsf + WS_IDX);
    short* ehl     = (short*)(wsf + WS_EHL);
    int*   list    = (int*)(wsf + WS_LIST);

    hipMemsetAsync(d_ws, 0, WS_ZERO_BYTES, stream);

    k_prep       <<<2,    256, 0, stream>>>(emb, enorm, ehl);
    k_argmin_mfma<<<512,  256, 0, stream>>>(x, ehl, enorm, idx, flagcnt, list);
    k_refine     <<<256,  256, 0, stream>>>(x, emb, enorm, list, flagcnt, idx);
    k_hist       <<<64,   256, 0, stream>>>(idx, cntp);
    k_scatter    <<<512,  512, 0, stream>>>(x, emb, idx, out + OUT_QUANT, dwp, lossbuf);
    k_final      <<<1,    512, 0, stream>>>(cntp, ema_cs, lossbuf, out);
    k_emb        <<<128,  256, 0, stream>>>(ema_w, dwp, out + OUT_SM, out + OUT_EMAW,
                                            out + OUT_EMB);
}

// Round 9
// 133.600 us; speedup vs baseline: 4.7390x; 1.0245x over previous
//
#include <hip/hip_runtime.h>
#include <hip/hip_bf16.h>
#include <math.h>

typedef __attribute__((ext_vector_type(8))) short short8;
typedef __attribute__((ext_vector_type(4))) float f32x4;

// Problem constants: B=32, D=64, H=W=64, K=512
#define KC      512
#define DD      64
#define NROWS   131072
#define HWN     4096
#define BSTRIDE 262144
#define TOTELEM 8388608.0f
#define MARGIN  0.03f

// ---- workspace layout (float offsets) ----
#define WS_LOSSBUF 0        // [2048] f  per-block loss (plain stores)
#define WS_FLAGC   2048     // [1] int (pad to 2080)
#define WS_CNTP    2080     // [8*512] f count partials
#define WS_DWP     6176     // [8*64*512] f dw partials dwp[g][d][k]
#define WS_EMBT    268320   // [64*512] f embT[d][k]
#define WS_ENORM   301088   // [512] f
#define WS_IDX     301600   // [131072] int
#define WS_EHL     432672   // [65536] short (byte off 1730688, 16B aligned)
#define WS_LIST    465440   // [131072] int
#define WS_ZERO_BYTES 1073280  // lossbuf..dwp end (268320 floats)

// ---- output layout (float offsets) ----
#define OUT_QUANT 0
#define OUT_LOSS  8388608
#define OUT_PERP  8388609
#define OUT_EMB   8388610
#define OUT_SM    8421378
#define OUT_EMAW  8421890

// RNE float->bf16 split: v ~= hi + lo (each bf16), error ~2^-18 relative
__device__ __forceinline__ void bfsplit(float v, short& h, short& l) {
    unsigned u  = __float_as_uint(v);
    unsigned hb = (u + 0x7FFFu + ((u >> 16) & 1u)) & 0xFFFF0000u;
    h = (short)(hb >> 16);
    float lo = v - __uint_as_float(hb);
    unsigned u2 = __float_as_uint(lo);
    l = (short)((u2 + 0x7FFFu + ((u2 >> 16) & 1u)) >> 16);
}

// K0: per-code norms + bf16 hi/lo B-fragments + embT transpose (for scatter).
__global__ void k_prep(const float* __restrict__ emb, float* __restrict__ enorm,
                       short* __restrict__ ehl, float* __restrict__ embT) {
    int k = blockIdx.x * 256 + threadIdx.x;
    if (k >= KC) return;
    const float* r = emb + k * DD;
    float s0 = 0.f, s1 = 0.f, s2 = 0.f, s3 = 0.f;
#pragma unroll
    for (int d = 0; d < DD; d += 4) {
        s0 += r[d] * r[d];
        s1 += r[d + 1] * r[d + 1];
        s2 += r[d + 2] * r[d + 2];
        s3 += r[d + 3] * r[d + 3];
    }
    enorm[k] = (s0 + s1) + (s2 + s3);
    int nt = k >> 4, cl = k & 15;
#pragma unroll
    for (int d = 0; d < DD; ++d) {
        float v = r[d];
        embT[d * KC + k] = v;
        short hh, ll;
        bfsplit(v, hh, ll);
        int ks = d >> 5, q = (d & 31) >> 3, i = d & 7;
        int lane = q * 16 + cl;
        ehl[((nt * 2 + ks) * 2 + 0) * 512 + lane * 8 + i] = hh;
        ehl[((nt * 2 + ks) * 2 + 1) * 512 + lane * 8 + i] = ll;
    }
}

// K1: MFMA argmin. 1024 blocks x 256 thr (4 waves); wave owns 32 rows (2 m-tiles)
// x all 512 codes. Next-nt B-fragments prefetched into registers.
__global__ __launch_bounds__(256, 4) void k_argmin_mfma(
        const float* __restrict__ x, const short* __restrict__ ehl,
        const float* __restrict__ enorm, int* __restrict__ idx_out,
        int* __restrict__ flagcnt, int* __restrict__ list) {
    const int tid  = threadIdx.x;
    const int w    = tid >> 6;
    const int lane = tid & 63;
    const int lm   = lane & 15, lq = lane >> 4;
    const int rowbase = blockIdx.x * 128 + w * 32;
    const int bb = rowbase >> 12, hw0 = rowbase & 4095;
    const float* xb = x + bb * BSTRIDE + hw0;

    short8 ah[2][2], al[2][2];
    float  fnj[2][4];
#pragma unroll
    for (int mt = 0; mt < 2; ++mt) {
        float xv[16];
#pragma unroll
        for (int ks = 0; ks < 2; ++ks)
#pragma unroll
            for (int i = 0; i < 8; ++i) {
                int d = ks * 32 + lq * 8 + i;
                xv[ks * 8 + i] = xb[d * HWN + mt * 16 + lm];
            }
        float p0 = 0.f, p1 = 0.f, p2 = 0.f, p3 = 0.f;
#pragma unroll
        for (int t = 0; t < 16; t += 4) {
            p0 += xv[t] * xv[t];
            p1 += xv[t + 1] * xv[t + 1];
            p2 += xv[t + 2] * xv[t + 2];
            p3 += xv[t + 3] * xv[t + 3];
        }
        float fn = (p0 + p1) + (p2 + p3);
        fn += __shfl_xor(fn, 16);
        fn += __shfl_xor(fn, 32);
#pragma unroll
        for (int j = 0; j < 4; ++j) fnj[mt][j] = __shfl(fn, lq * 4 + j);
#pragma unroll
        for (int ks = 0; ks < 2; ++ks) {
            short8 h8, l8;
#pragma unroll
            for (int i = 0; i < 8; ++i) {
                short hh, ll;
                bfsplit(xv[ks * 8 + i], hh, ll);
                h8[i] = hh; l8[i] = ll;
            }
            ah[mt][ks] = h8; al[mt][ks] = l8;
        }
    }

    const short8* eb = (const short8*)ehl;
    float best[2][4], best2[2][4];
    int   bi[2][4];
#pragma unroll
    for (int mt = 0; mt < 2; ++mt)
#pragma unroll
        for (int j = 0; j < 4; ++j) { best[mt][j] = 3.4e38f; best2[mt][j] = 3.4e38f; bi[mt][j] = 0; }

    // register prefetch pipeline over nt
    short8 nh0 = eb[0 * 64 + lane], nl0 = eb[1 * 64 + lane];
    short8 nh1 = eb[2 * 64 + lane], nl1 = eb[3 * 64 + lane];
#pragma unroll 1
    for (int nt = 0; nt < 32; ++nt) {
        short8 bh0 = nh0, bl0 = nl0, bh1 = nh1, bl1 = nl1;
        if (nt < 31) {
            nh0 = eb[((nt + 1) * 4 + 0) * 64 + lane];
            nl0 = eb[((nt + 1) * 4 + 1) * 64 + lane];
            nh1 = eb[((nt + 1) * 4 + 2) * 64 + lane];
            nl1 = eb[((nt + 1) * 4 + 3) * 64 + lane];
        }
        float en = enorm[nt * 16 + lm];
        const int c = nt * 16 + lm;
#pragma unroll
        for (int mt = 0; mt < 2; ++mt) {
            f32x4 acc = {0.f, 0.f, 0.f, 0.f};
            acc = __builtin_amdgcn_mfma_f32_16x16x32_bf16(ah[mt][0], bh0, acc, 0, 0, 0);
            acc = __builtin_amdgcn_mfma_f32_16x16x32_bf16(al[mt][0], bh0, acc, 0, 0, 0);
            acc = __builtin_amdgcn_mfma_f32_16x16x32_bf16(ah[mt][0], bl0, acc, 0, 0, 0);
            acc = __builtin_amdgcn_mfma_f32_16x16x32_bf16(ah[mt][1], bh1, acc, 0, 0, 0);
            acc = __builtin_amdgcn_mfma_f32_16x16x32_bf16(al[mt][1], bh1, acc, 0, 0, 0);
            acc = __builtin_amdgcn_mfma_f32_16x16x32_bf16(ah[mt][1], bl1, acc, 0, 0, 0);
#pragma unroll
            for (int j = 0; j < 4; ++j) {
                float dist = fnj[mt][j] + en - 2.0f * acc[j];
                bool  lt   = dist < best[mt][j];
                best2[mt][j] = lt ? best[mt][j] : fminf(best2[mt][j], dist);
                bi[mt][j]    = lt ? c : bi[mt][j];
                best[mt][j]  = lt ? dist : best[mt][j];
            }
        }
    }

#pragma unroll
    for (int mt = 0; mt < 2; ++mt)
#pragma unroll
        for (int j = 0; j < 4; ++j) {
            float b = best[mt][j], b2 = best2[mt][j];
            int   ii = bi[mt][j];
#pragma unroll
            for (int o = 1; o < 16; o <<= 1) {
                float ob  = __shfl_xor(b, o);
                float ob2 = __shfl_xor(b2, o);
                int   oi  = __shfl_xor(ii, o);
                bool take = (ob < b) || (ob == b && oi < ii);
                float lose = take ? b : ob;
                b2 = fminf(lose, fminf(b2, ob2));
                b  = take ? ob : b;
                ii = take ? oi : ii;
            }
            if (lm == 0) {
                int row = rowbase + mt * 16 + lq * 4 + j;
                idx_out[row] = ii;
                if (b2 - b < MARGIN) {
                    int p = atomicAdd(flagcnt, 1);
                    list[p] = row;
                }
            }
        }
}

// K2: exact fp32 re-argmin for flagged rows.
__global__ void k_refine(const float* __restrict__ x, const float* __restrict__ emb,
                         const float* __restrict__ enorm, const int* __restrict__ list,
                         const int* __restrict__ flagcnt, int* __restrict__ idx_out) {
    const int gw   = (blockIdx.x * 256 + threadIdx.x) >> 6;
    const int lane = threadIdx.x & 63;
    const int nw   = gridDim.x * 4;
    const int total = *flagcnt;
    for (int t = gw; t < total; t += nw) {
        int row = list[t];
        int b = row >> 12, hw = row & 4095;
        const float* xp = x + b * BSTRIDE + hw;
        float r[64];
#pragma unroll
        for (int d = 0; d < 64; ++d) r[d] = xp[d * HWN];
        float f0 = 0.f, f1 = 0.f, f2 = 0.f, f3 = 0.f;
#pragma unroll
        for (int d = 0; d < 64; d += 4) {
            f0 += r[d] * r[d]; f1 += r[d + 1] * r[d + 1];
            f2 += r[d + 2] * r[d + 2]; f3 += r[d + 3] * r[d + 3];
        }
        float fn = (f0 + f1) + (f2 + f3);
        float best = 3.4e38f; int bi = 0;
        for (int c0 = 0; c0 < 8; ++c0) {
            int k = c0 * 64 + lane;
            const float* e = emb + k * DD;
            float a0 = 0.f, a1 = 0.f, a2 = 0.f, a3 = 0.f;
#pragma unroll
            for (int d = 0; d < 64; d += 4) {
                a0 += r[d] * e[d]; a1 += r[d + 1] * e[d + 1];
                a2 += r[d + 2] * e[d + 2]; a3 += r[d + 3] * e[d + 3];
            }
            float dist = fn - 2.0f * ((a0 + a1) + (a2 + a3)) + enorm[k];
            if (dist < best) { best = dist; bi = k; }
        }
#pragma unroll
        for (int o = 1; o < 64; o <<= 1) {
            float ob = __shfl_xor(best, o);
            int   oi = __shfl_xor(bi, o);
            if (ob < best || (ob == best && oi < bi)) { best = ob; bi = oi; }
        }
        if (lane == 0) idx_out[row] = bi;
    }
}

// K3: counts histogram -> 8-way partials
__global__ void k_hist(const int* __restrict__ idx, float* __restrict__ cntp) {
    __shared__ float h[KC];
    const int tid = threadIdx.x;
    for (int i = tid; i < KC; i += 256) h[i] = 0.f;
    __syncthreads();
    const int stride = gridDim.x * 256;
    for (int t = blockIdx.x * 256 + tid; t < NROWS; t += stride)
        atomicAdd(&h[idx[t]], 1.0f);
    __syncthreads();
    float* cp = cntp + (blockIdx.x & 7) * KC;
    for (int i = tid; i < KC; i += 256) {
        float v = h[i];
        if (v != 0.f) atomicAdd(&cp[i], v);   // integer-valued: exact
    }
}

// K4: quant_st + loss + dw. 2048 blocks x 256 thr, one (b,d) plane each.
// embT gives coalesced column stage; dw flush = coalesced 8-way atomic partials.
__global__ __launch_bounds__(256) void k_scatter(
        const float* __restrict__ x, const float* __restrict__ embT,
        const int* __restrict__ idx, float* __restrict__ qout,
        float* __restrict__ dwp, float* __restrict__ lossbuf) {
    __shared__ float dwloc[KC];
    __shared__ float ecol[KC];
    __shared__ float red[4];
    const int bid = blockIdx.x;
    const int b = bid >> 6, d = bid & 63;
    const int tid = threadIdx.x;   // 256

    for (int i = tid; i < KC; i += 256) {
        dwloc[i] = 0.f;
        ecol[i]  = embT[d * KC + i];   // coalesced 2KB stage
    }
    __syncthreads();

    const float4* xp4 = (const float4*)(x + b * BSTRIDE + d * HWN);
    float4*       qp4 = (float4*)(qout + b * BSTRIDE + d * HWN);
    const int4*   ip4 = (const int4*)(idx + b * HWN);

    float ls = 0.f;
#pragma unroll
    for (int it = 0; it < 4; ++it) {
        int c4 = it * 256 + tid;          // 1024 float4 per plane
        float4 xv = xp4[c4];
        int4   iv = ip4[c4];
        float4 qv;
        float e0 = ecol[iv.x], e1 = ecol[iv.y], e2 = ecol[iv.z], e3 = ecol[iv.w];
        float t0 = e0 - xv.x, t1 = e1 - xv.y, t2 = e2 - xv.z, t3 = e3 - xv.w;
        qv.x = xv.x + t0; qv.y = xv.y + t1; qv.z = xv.z + t2; qv.w = xv.w + t3;
        qp4[c4] = qv;
        ls += t0 * t0 + t1 * t1 + t2 * t2 + t3 * t3;
        atomicAdd(&dwloc[iv.x], xv.x);
        atomicAdd(&dwloc[iv.y], xv.y);
        atomicAdd(&dwloc[iv.z], xv.z);
        atomicAdd(&dwloc[iv.w], xv.w);
    }

#pragma unroll
    for (int o = 32; o > 0; o >>= 1) ls += __shfl_down(ls, o);
    if ((tid & 63) == 0) red[tid >> 6] = ls;
    __syncthreads();
    if (tid == 0)
        lossbuf[bid] = (red[0] + red[1]) + (red[2] + red[3]);  // plain store

    float* dp = dwp + ((b & 7) * DD + d) * KC;
    for (int i = tid; i < KC; i += 256)
        atomicAdd(&dp[i], dwloc[i]);      // coalesced lanes, 4 contenders/slot
}

// K5: scalars + smoothed cluster sizes
__global__ void k_final(const float* __restrict__ cntp, const float* __restrict__ ema_cs,
                        const float* __restrict__ lossbuf, float* __restrict__ out) {
    __shared__ float r1[8], r2[8], r3[8];
    __shared__ float nb;
    const int t = threadIdx.x;   // 512

    float c = 0.f;
#pragma unroll
    for (int g = 0; g < 8; ++g) c += cntp[g * KC + t];
    float ncs = 0.99f * ema_cs[t] + 0.01f * c;

    float s = ncs;
    float p = c * (1.0f / 131072.0f);
    float e = (p > 0.f) ? p * logf(p) : 0.f;
    float lv = lossbuf[t] + lossbuf[t + 512] + lossbuf[t + 1024] + lossbuf[t + 1536];
#pragma unroll
    for (int o = 32; o > 0; o >>= 1) {
        s  += __shfl_down(s, o);
        e  += __shfl_down(e, o);
        lv += __shfl_down(lv, o);
    }
    if ((t & 63) == 0) { int w = t >> 6; r1[w] = s; r2[w] = e; r3[w] = lv; }
    __syncthreads();
    if (t == 0) {
        float n = 0.f, es = 0.f, lt = 0.f;
#pragma unroll
        for (int i = 0; i < 8; ++i) { n += r1[i]; es += r2[i]; lt += r3[i]; }
        nb = n;
        out[OUT_LOSS] = 0.25f * (lt / TOTELEM);
        out[OUT_PERP] = expf(-es);
    }
    __syncthreads();
    float n = nb;
    out[OUT_SM + t] = (ncs + 1e-5f) / (n + 0.00512f) * n;
}

// K6: reduce dw partials + new_ema_w + new_embedding
__global__ void k_emb(const float* __restrict__ ema_w, const float* __restrict__ dwp,
                      const float* __restrict__ sm, float* __restrict__ out_emaw,
                      float* __restrict__ out_emb) {
    int i = blockIdx.x * 256 + threadIdx.x;   // i = k*64 + d
    int k = i >> 6, d = i & 63;
    float dw = 0.f;
#pragma unroll
    for (int g = 0; g < 8; ++g) dw += dwp[(g * DD + d) * KC + k];
    float nw = 0.99f * ema_w[i] + 0.01f * dw;
    out_emaw[i] = nw;
    out_emb[i]  = nw / sm[k];
}

extern "C" void kernel_launch(void* const* d_in, const int* in_sizes, int n_in,
                              void* d_out, int out_size, void* d_ws, size_t ws_size,
                              hipStream_t stream) {
    const float* x      = (const float*)d_in[0];
    const float* emb    = (const float*)d_in[1];
    const float* ema_cs = (const float*)d_in[2];
    const float* ema_w  = (const float*)d_in[3];
    float* out = (float*)d_out;

    float* wsf     = (float*)d_ws;
    float* lossbuf = wsf + WS_LOSSBUF;
    int*   flagcnt = (int*)(wsf + WS_FLAGC);
    float* cntp    = wsf + WS_CNTP;
    float* dwp     = wsf + WS_DWP;
    float* embT    = wsf + WS_EMBT;
    float* enorm   = wsf + WS_ENORM;
    int*   idx     = (int*)(wsf + WS_IDX);
    short* ehl     = (short*)(wsf + WS_EHL);
    int*   list    = (int*)(wsf + WS_LIST);

    hipMemsetAsync(d_ws, 0, WS_ZERO_BYTES, stream);

    k_prep       <<<2,    256, 0, stream>>>(emb, enorm, ehl, embT);
    k_argmin_mfma<<<1024, 256, 0, stream>>>(x, ehl, enorm, idx, flagcnt, list);
    k_refine     <<<256,  256, 0, stream>>>(x, emb, enorm, list, flagcnt, idx);
    k_hist       <<<64,   256, 0, stream>>>(idx, cntp);
    k_scatter    <<<2048, 256, 0, stream>>>(x, embT, idx, out + OUT_QUANT, dwp, lossbuf);
    k_final      <<<1,    512, 0, stream>>>(cntp, ema_cs, lossbuf, out);
    k_emb        <<<128,  256, 0, stream>>>(ema_w, dwp, out + OUT_SM, out + OUT_EMAW,
                                            out + OUT_EMB);
}